// Round 4
// baseline (704.952 us; speedup 1.0000x reference)
//
#include <hip/hip_runtime.h>

#define NN 40000
#define SS 16
#define CC 96
#define GG 12
#define CP 100   // padded LDS row stride (floats)

typedef __attribute__((ext_vector_type(8))) short bf16x8;
typedef __attribute__((ext_vector_type(4))) float f32x4;

// float -> bf16 (RNE), raw 16-bit pattern
__device__ __forceinline__ short f2bf(float f) {
    union { float f; unsigned u; } c; c.f = f;
    unsigned r = (c.u + 0x7fffu + ((c.u >> 16) & 1u)) >> 16;
    return (short)r;
}

// ---- DPP cross-lane (within rows of 16 lanes; ~2 cyc vs 120 for ds_bpermute) ----
template<int CTRL>
__device__ __forceinline__ float dppf(float x) {
    int r = __builtin_amdgcn_mov_dpp(__float_as_int(x), CTRL, 0xF, 0xF, true);
    return __int_as_float(r);
}
// full 16-lane allreduce sum: quad swap1, swap2, half-mirror (cross-quad in 8), mirror (cross-8)
__device__ __forceinline__ float row16_sum(float x) {
    x += dppf<0xB1>(x);    // quad_perm [1,0,3,2]
    x += dppf<0x4E>(x);    // quad_perm [2,3,0,1]
    x += dppf<0x141>(x);   // ROW_HALF_MIRROR
    x += dppf<0x140>(x);   // ROW_MIRROR
    return x;
}
__device__ __forceinline__ float row16_max(float x) {
    x = fmaxf(x, dppf<0xB1>(x));
    x = fmaxf(x, dppf<0x4E>(x));
    x = fmaxf(x, dppf<0x141>(x));
    x = fmaxf(x, dppf<0x140>(x));
    return x;
}

// ---------------- prep: Wfused = Wp2 @ Ww1, cfused = bp2 @ Ww1 + bw1 ----------------
__global__ void fuse_kernel(const float* __restrict__ Wp2, const float* __restrict__ Ww1,
                            const float* __restrict__ bp2, const float* __restrict__ bw1,
                            float* __restrict__ Wfused, float* __restrict__ cfused)
{
    const int o = blockIdx.x*256 + threadIdx.x;
    if (o < CC*GG) {
        const int i = o / GG, g = o % GG;
        float s = 0.f;
        for (int j = 0; j < CC; ++j) s += Wp2[i*CC + j] * Ww1[j*GG + g];
        Wfused[o] = s;
    }
    if (o < GG) {
        float s = bw1[o];
        for (int j = 0; j < CC; ++j) s += bp2[j] * Ww1[j*GG + o];
        cfused[o] = s;
    }
}

// ---------------- Kernel A: q/k/v projections via MFMA ----------------
// grid (625, 3): one 16-row tile per wave. W staged as bf16 B-frags in LDS.
// p=0: qw1 = relu(ln(q@Wq+bq))@Ww1 [N,12]; p=1: kw1 likewise; p=2: val = v@Wv+bv [N,96]
__global__ __launch_bounds__(256) void qkv_mfma(
    const float* __restrict__ q, const float* __restrict__ kx, const float* __restrict__ v,
    const float* __restrict__ Wq, const float* __restrict__ bq, const float* __restrict__ gq, const float* __restrict__ betaq,
    const float* __restrict__ Wk, const float* __restrict__ bk, const float* __restrict__ gk, const float* __restrict__ betak,
    const float* __restrict__ Wv, const float* __restrict__ bv,
    const float* __restrict__ Ww1,
    float* __restrict__ valout, float* __restrict__ qw1out, float* __restrict__ kw1out)
{
    __shared__ ushort sWf[18*64*8];     // W B-frags bf16, 18 KB
    __shared__ float sbias[CC], sg[CC], sbeta[CC];
    __shared__ float sx[4][SS*CP];      // per-wave C/D->A transpose buffer

    const int p = blockIdx.y;
    const float* X; const float* W; const float* b;
    const float* g = nullptr; const float* beta = nullptr;
    if (p == 0)      { X = q;  W = Wq; b = bq; g = gq; beta = betaq; }
    else if (p == 1) { X = kx; W = Wk; b = bk; g = gk; beta = betak; }
    else             { X = v;  W = Wv; b = bv; }
    const bool has_ln = (p < 2);
    float* w1out = (p == 0) ? qw1out : kw1out;

    const int t = threadIdx.x;
    if (t < CC) {
        sbias[t] = b[t];
        if (has_ln) { sg[t] = g[t]; sbeta[t] = beta[t]; }
    }
    for (int idx = t; idx < 18*64; idx += 256) {
        const int ntkb = idx >> 6, ln = idx & 63;
        const int nt = ntkb / 3, kb = ntkb - nt*3;
        const int ccol  = nt*16 + (ln & 15);
        const int kbase = kb*32 + (ln >> 4)*8;
        ushort* dst = sWf + idx*8;
        #pragma unroll
        for (int j = 0; j < 8; ++j) dst[j] = (ushort)f2bf(W[(size_t)(kbase + j)*CC + ccol]);
    }

    const int lane = t & 63, w = t >> 6;
    const int c16 = lane & 15, quad = lane >> 4;

    bf16x8 Ww1f[3];
    if (has_ln) {
        #pragma unroll
        for (int kb = 0; kb < 3; ++kb)
            #pragma unroll
            for (int j = 0; j < 8; ++j)
                Ww1f[kb][j] = (c16 < GG) ? f2bf(Ww1[(size_t)(kb*32 + quad*8 + j)*GG + c16]) : (short)0;
    }

    __syncthreads();

    const f32x4 zero4 = {0.f, 0.f, 0.f, 0.f};
    float* sxw = sx[w];
    const int tile = blockIdx.x*4 + w;     // exactly 2500 tiles
    const int row0 = tile * 16;

    const float* xr = X + (size_t)(row0 + c16)*CC;
    bf16x8 Af[3];
    #pragma unroll
    for (int kb = 0; kb < 3; ++kb) {
        const float4 a0 = *(const float4*)(xr + kb*32 + quad*8);
        const float4 a1 = *(const float4*)(xr + kb*32 + quad*8 + 4);
        Af[kb][0] = f2bf(a0.x); Af[kb][1] = f2bf(a0.y);
        Af[kb][2] = f2bf(a0.z); Af[kb][3] = f2bf(a0.w);
        Af[kb][4] = f2bf(a1.x); Af[kb][5] = f2bf(a1.y);
        Af[kb][6] = f2bf(a1.z); Af[kb][7] = f2bf(a1.w);
    }

    f32x4 acc[6];
    #pragma unroll
    for (int nt = 0; nt < 6; ++nt) acc[nt] = zero4;
    #pragma unroll
    for (int kb = 0; kb < 3; ++kb)
        #pragma unroll
        for (int nt = 0; nt < 6; ++nt) {
            const bf16x8 bf = *(const bf16x8*)(sWf + ((nt*3 + kb)*64 + lane)*8);
            acc[nt] = __builtin_amdgcn_mfma_f32_16x16x32_bf16(Af[kb], bf, acc[nt], 0, 0, 0);
        }

    #pragma unroll
    for (int nt = 0; nt < 6; ++nt) {
        const float bb = sbias[nt*16 + c16];
        #pragma unroll
        for (int r = 0; r < 4; ++r) acc[nt][r] += bb;
    }

    if (has_ln) {
        #pragma unroll
        for (int r = 0; r < 4; ++r) {
            float sum = 0.f, sq = 0.f;
            #pragma unroll
            for (int nt = 0; nt < 6; ++nt) { float x = acc[nt][r]; sum += x; sq += x*x; }
            sum = row16_sum(sum); sq = row16_sum(sq);
            const float mu  = sum * (1.f/96.f);
            const float var = sq * (1.f/96.f) - mu*mu;
            const float rs  = rsqrtf(var + 1e-5f);
            #pragma unroll
            for (int nt = 0; nt < 6; ++nt) {
                const int c = nt*16 + c16;
                acc[nt][r] = fmaxf((acc[nt][r] - mu)*rs*sg[c] + sbeta[c], 0.f);
            }
        }
        // C/D -> per-wave LDS -> A-frags -> @Ww1
        #pragma unroll
        for (int nt = 0; nt < 6; ++nt)
            #pragma unroll
            for (int r = 0; r < 4; ++r)
                sxw[(quad*4 + r)*CP + nt*16 + c16] = acc[nt][r];

        bf16x8 aA[3];
        #pragma unroll
        for (int kb = 0; kb < 3; ++kb) {
            const float4 a0 = *(const float4*)(sxw + c16*CP + kb*32 + quad*8);
            const float4 a1 = *(const float4*)(sxw + c16*CP + kb*32 + quad*8 + 4);
            aA[kb][0] = f2bf(a0.x); aA[kb][1] = f2bf(a0.y);
            aA[kb][2] = f2bf(a0.z); aA[kb][3] = f2bf(a0.w);
            aA[kb][4] = f2bf(a1.x); aA[kb][5] = f2bf(a1.y);
            aA[kb][6] = f2bf(a1.z); aA[kb][7] = f2bf(a1.w);
        }
        f32x4 o = zero4;
        #pragma unroll
        for (int kb = 0; kb < 3; ++kb)
            o = __builtin_amdgcn_mfma_f32_16x16x32_bf16(aA[kb], Ww1f[kb], o, 0, 0, 0);
        if (c16 < GG) {
            #pragma unroll
            for (int r = 0; r < 4; ++r)
                w1out[(size_t)(row0 + quad*4 + r)*GG + c16] = o[r];
        }
    } else {
        #pragma unroll
        for (int r = 0; r < 4; ++r)
            #pragma unroll
            for (int nt = 0; nt < 6; ++nt)
                valout[(size_t)(row0 + quad*4 + r)*CC + nt*16 + c16] = acc[nt][r];
    }
}

// ---------------- Kernel B: grouped vector attention, one node per wave ----------------
__global__ __launch_bounds__(256, 3) void attn2(
    const float* __restrict__ xyz, const int* __restrict__ refidx,
    const float* __restrict__ Wp1, const float* __restrict__ bp1,
    const float* __restrict__ gp,  const float* __restrict__ betap,
    const float* __restrict__ Wp2, const float* __restrict__ bp2,
    const float* __restrict__ gw,  const float* __restrict__ betaw,
    const float* __restrict__ Ww2, const float* __restrict__ bw2,
    const float* __restrict__ Wfused, const float* __restrict__ cfused,
    const float* __restrict__ valw, const float* __restrict__ kw1w, const float* __restrict__ qw1w,
    float* __restrict__ out)
{
    __shared__ float  sWp1[3*CC];
    __shared__ float  sbp1[CC], sgp[CC], sbetap[CC], sbp2[CC];
    __shared__ float  sWw2[GG*GG];
    __shared__ float  sgw[16], sbetaw[16], sbw2[16], scf[16];
    __shared__ ushort sWp2f[18*64*8];     // Wp2 B-frags bf16, 18 KB
    __shared__ float  ybv[4][SS*GG];
    __shared__ float  swv[4][SS*GG];
    __shared__ float  soutb[4][CC];

    const int t = threadIdx.x;
    for (int i = t; i < 3*CC; i += 256) sWp1[i] = Wp1[i];
    if (t < CC) { sbp1[t] = bp1[t]; sgp[t] = gp[t]; sbetap[t] = betap[t]; sbp2[t] = bp2[t]; }
    if (t < GG*GG) sWw2[t] = Ww2[t];
    if (t < 16) {
        sgw[t]    = (t < GG) ? gw[t]     : 0.f;
        sbetaw[t] = (t < GG) ? betaw[t]  : 0.f;
        sbw2[t]   = (t < GG) ? bw2[t]    : 0.f;
        scf[t]    = (t < GG) ? cfused[t] : 0.f;
    }
    for (int idx = t; idx < 18*64; idx += 256) {
        const int ntkb = idx >> 6, ln = idx & 63;
        const int nt = ntkb / 3, kb = ntkb - nt*3;
        const int ccol  = nt*16 + (ln & 15);
        const int kbase = kb*32 + (ln >> 4)*8;
        ushort* dst = sWp2f + idx*8;
        #pragma unroll
        for (int j = 0; j < 8; ++j) dst[j] = (ushort)f2bf(Wp2[(size_t)(kbase + j)*CC + ccol]);
    }

    const int lane = t & 63, w = t >> 6;
    const int c16 = lane & 15, quad = lane >> 4;
    const int gcl = (c16 < GG) ? c16 : (GG-1);

    bf16x8 Wff[3];   // Wfused B-frags (cols 12..15 zero)
    #pragma unroll
    for (int kb = 0; kb < 3; ++kb)
        #pragma unroll
        for (int j = 0; j < 8; ++j)
            Wff[kb][j] = (c16 < GG) ? f2bf(Wfused[(size_t)(kb*32 + quad*8 + j)*GG + c16]) : (short)0;

    __syncthreads();   // staging done; below is wave-synchronous

    float* yb = ybv[w];
    float* sw = swv[w];
    float* so = soutb[w];
    const f32x4 zero4 = {0.f, 0.f, 0.f, 0.f};

    const int nbase = blockIdx.x*16 + w*4;

    for (int i = 0; i < 4; ++i) {
        const int n = nbase + i;

        // ---- per-lane neighbor (s = c16) for gathers / t1 ----
        const int   id   = refidx[(size_t)n*SS + c16];
        const float m    = (id >= 0) ? 1.f : 0.f;
        const int   safe = (id < 0) ? 0 : id;

        // ---- C/D-layout epilogue operands (s = quad*4+r), gathered directly ----
        float kwv[4];
        #pragma unroll
        for (int r = 0; r < 4; ++r) {
            const int sid = refidx[(size_t)n*SS + quad*4 + r];
            const float mr = (sid >= 0) ? 1.f : 0.f;
            const int sf = (sid < 0) ? 0 : sid;
            kwv[r] = kw1w[(size_t)sf*GG + gcl] * mr;
        }
        const float qv = qw1w[(size_t)n*GG + gcl];

        // ---- val gather (A-layout: lane s=c16, cols kb*32+quad*8+..) ----
        const float* vr = valw + (size_t)safe*CC;
        float4 v0[3], v1[3];
        #pragma unroll
        for (int kb = 0; kb < 3; ++kb) {
            v0[kb] = *(const float4*)(vr + kb*32 + quad*8);
            v1[kb] = *(const float4*)(vr + kb*32 + quad*8 + 4);
        }

        const float px = (xyz[(size_t)safe*3 + 0] - xyz[(size_t)n*3 + 0]) * m;
        const float py = (xyz[(size_t)safe*3 + 1] - xyz[(size_t)n*3 + 1]) * m;
        const float pz = (xyz[(size_t)safe*3 + 2] - xyz[(size_t)n*3 + 2]) * m;

        // ---- t1 = relu(ln(pos @ Wp1 + bp1)) in A-frag layout ----
        float tv[3][8];
        float sum = 0.f, sq = 0.f;
        #pragma unroll
        for (int kb = 0; kb < 3; ++kb)
            #pragma unroll
            for (int j = 0; j < 8; ++j) {
                const int c = kb*32 + quad*8 + j;
                const float x = sbp1[c] + px*sWp1[c] + py*sWp1[CC + c] + pz*sWp1[2*CC + c];
                tv[kb][j] = x; sum += x; sq += x*x;
            }
        sum += __shfl_xor(sum, 16, 64); sq += __shfl_xor(sq, 16, 64);
        sum += __shfl_xor(sum, 32, 64); sq += __shfl_xor(sq, 32, 64);
        const float mu1  = sum * (1.f/96.f);
        const float var1 = sq * (1.f/96.f) - mu1*mu1;
        const float rs1  = rsqrtf(var1 + 1e-5f);
        bf16x8 t1A[3];
        #pragma unroll
        for (int kb = 0; kb < 3; ++kb)
            #pragma unroll
            for (int j = 0; j < 8; ++j) {
                const int c = kb*32 + quad*8 + j;
                t1A[kb][j] = f2bf(fmaxf((tv[kb][j] - mu1)*rs1*sgp[c] + sbetap[c], 0.f));
            }

        // ---- t2 = t1 @ Wfused; peb = t1 @ Wp2 (frags from LDS) ----
        f32x4 t2 = zero4;
        #pragma unroll
        for (int kb = 0; kb < 3; ++kb)
            t2 = __builtin_amdgcn_mfma_f32_16x16x32_bf16(t1A[kb], Wff[kb], t2, 0, 0, 0);

        f32x4 pacc[6];
        #pragma unroll
        for (int nt = 0; nt < 6; ++nt) pacc[nt] = zero4;
        #pragma unroll
        for (int kb = 0; kb < 3; ++kb)
            #pragma unroll
            for (int nt = 0; nt < 6; ++nt) {
                const bf16x8 bf = *(const bf16x8*)(sWp2f + ((nt*3 + kb)*64 + lane)*8);
                pacc[nt] = __builtin_amdgcn_mfma_f32_16x16x32_bf16(t1A[kb], bf, pacc[nt], 0, 0, 0);
            }

        // ---- t2 epilogue: + m*kw1[safe[s]][g] - qw1[n][g] + cfused[g] ----
        #pragma unroll
        for (int r = 0; r < 4; ++r)
            t2[r] += kwv[r] - qv + scf[c16];

        // LN over G=12 (rows s=quad*4+r, lane col g=c16) via DPP
        #pragma unroll
        for (int r = 0; r < 4; ++r) {
            const float x = (c16 < GG) ? t2[r] : 0.f;
            const float s1 = row16_sum(x);
            const float s2 = row16_sum(x*x);
            const float mu  = s1 * (1.f/12.f);
            const float var = s2 * (1.f/12.f) - mu*mu;
            const float rs  = rsqrtf(var + 1e-5f);
            const float y   = fmaxf((t2[r] - mu)*rs*sgw[c16] + sbetaw[c16], 0.f);
            if (c16 < GG) yb[(quad*4 + r)*GG + c16] = y;
        }

        // w3 = y @ Ww2 + bw2 ; lane covers s=c16, g' in {quad, quad+4, quad+8}
        float w3[3];
        #pragma unroll
        for (int gi = 0; gi < 3; ++gi) {
            const int gpp = quad + gi*4;
            float a2 = sbw2[gpp];
            #pragma unroll
            for (int gg2 = 0; gg2 < GG; ++gg2)
                a2 += yb[c16*GG + gg2] * sWw2[gg2*GG + gpp];
            w3[gi] = a2;
        }

        // softmax over s (c16-lanes within each quad-row), then * mask — all DPP
        #pragma unroll
        for (int gi = 0; gi < 3; ++gi) {
            const float mx = row16_max(w3[gi]);
            const float e  = __expf(w3[gi] - mx);
            const float tot = row16_sum(e);
            w3[gi] = e / tot * m;
        }
        // broadcast w to LDS for the C/D-layout peb reduction
        #pragma unroll
        for (int gi = 0; gi < 3; ++gi)
            sw[c16*GG + quad + 4*gi] = w3[gi];

        // ---- valpart: sum_s val[s][col]*w[s][g(col)] via DPP allreduce, write direct ----
        #pragma unroll
        for (int kb = 0; kb < 3; ++kb) {
            const float pj[8] = {v0[kb].x, v0[kb].y, v0[kb].z, v0[kb].w,
                                 v1[kb].x, v1[kb].y, v1[kb].z, v1[kb].w};
            #pragma unroll
            for (int j = 0; j < 8; ++j) {
                const float pr = row16_sum(pj[j] * w3[kb]);
                if (c16 == 0) so[kb*32 + quad*8 + j] = pr;
            }
        }

        // ---- pebpart: consume pacc in C/D layout, reduce over s ----
        #pragma unroll
        for (int nt = 0; nt < 6; ++nt) {
            const float b2   = sbp2[nt*16 + c16];
            const int   gidx = 2*nt + (c16 >> 3);
            float a2 = 0.f;
            #pragma unroll
            for (int r = 0; r < 4; ++r)
                a2 += (pacc[nt][r] + b2) * sw[(quad*4 + r)*GG + gidx];
            a2 += __shfl_xor(a2, 16, 64);
            a2 += __shfl_xor(a2, 32, 64);
            if (quad == 0) so[nt*16 + c16] += a2;
        }

        if (lane < 24) {
            const float4 o4 = ((const float4*)so)[lane];
            ((float4*)(out + (size_t)n*CC))[lane] = o4;
        }
    }
}

extern "C" void kernel_launch(void* const* d_in, const int* in_sizes, int n_in,
                              void* d_out, int out_size, void* d_ws, size_t ws_size,
                              hipStream_t stream)
{
    const float* q     = (const float*)d_in[0];
    const float* k     = (const float*)d_in[1];
    const float* v     = (const float*)d_in[2];
    const float* xyz   = (const float*)d_in[3];
    const int*   ridx  = (const int*)d_in[4];
    const float* Wq    = (const float*)d_in[5];
    const float* bq    = (const float*)d_in[6];
    const float* gq    = (const float*)d_in[7];
    const float* betaq = (const float*)d_in[8];
    const float* Wk    = (const float*)d_in[9];
    const float* bk    = (const float*)d_in[10];
    const float* gk    = (const float*)d_in[11];
    const float* betak = (const float*)d_in[12];
    const float* Wv    = (const float*)d_in[13];
    const float* bv    = (const float*)d_in[14];
    const float* Wp1   = (const float*)d_in[15];
    const float* bp1   = (const float*)d_in[16];
    const float* gp    = (const float*)d_in[17];
    const float* betap = (const float*)d_in[18];
    const float* Wp2   = (const float*)d_in[19];
    const float* bp2   = (const float*)d_in[20];
    const float* Ww1   = (const float*)d_in[21];
    const float* bw1   = (const float*)d_in[22];
    const float* gw    = (const float*)d_in[23];
    const float* betaw = (const float*)d_in[24];
    const float* Ww2   = (const float*)d_in[25];
    const float* bw2   = (const float*)d_in[26];
    float* out = (float*)d_out;

    float* ws = (float*)d_ws;
    float* valw   = ws;                                    // [N, 96]
    float* kw1w   = ws + (size_t)NN*CC;                    // [N, 12]
    float* qw1w   = ws + (size_t)NN*CC + (size_t)NN*GG;    // [N, 12]
    float* Wfused = ws + (size_t)NN*CC + 2*(size_t)NN*GG;  // [96, 12]
    float* cfused = Wfused + CC*GG;                        // [12]

    fuse_kernel<<<dim3(5, 1, 1), 256, 0, stream>>>(Wp2, Ww1, bp2, bw1, Wfused, cfused);

    qkv_mfma<<<dim3(625, 3, 1), 256, 0, stream>>>(
        q, k, v, Wq, bq, gq, betaq, Wk, bk, gk, betak, Wv, bv, Ww1,
        valw, qw1w, kw1w);

    attn2<<<dim3(2500, 1, 1), 256, 0, stream>>>(
        xyz, ridx, Wp1, bp1, gp, betap, Wp2, bp2,
        gw, betaw, Ww2, bw2, Wfused, cfused,
        valw, kw1w, qw1w, out);
}

// Round 5
// 369.411 us; speedup vs baseline: 1.9083x; 1.9083x over previous
//
#include <hip/hip_runtime.h>

#define NN 40000
#define SS 16
#define CC 96
#define GG 12
#define CP 100   // padded LDS row stride (floats)

typedef __attribute__((ext_vector_type(8))) short bf16x8;
typedef __attribute__((ext_vector_type(4))) float f32x4;

// float -> bf16 (RNE), raw 16-bit pattern
__device__ __forceinline__ short f2bf(float f) {
    union { float f; unsigned u; } c; c.f = f;
    unsigned r = (c.u + 0x7fffu + ((c.u >> 16) & 1u)) >> 16;
    return (short)r;
}

// ---- DPP cross-lane (within rows of 16 lanes; ~2 cyc vs ~120 for ds_bpermute) ----
template<int CTRL>
__device__ __forceinline__ float dppf(float x) {
    int r = __builtin_amdgcn_mov_dpp(__float_as_int(x), CTRL, 0xF, 0xF, true);
    return __int_as_float(r);
}
__device__ __forceinline__ float row16_sum(float x) {
    x += dppf<0xB1>(x);    // quad_perm [1,0,3,2]
    x += dppf<0x4E>(x);    // quad_perm [2,3,0,1]
    x += dppf<0x141>(x);   // ROW_HALF_MIRROR
    x += dppf<0x140>(x);   // ROW_MIRROR
    return x;
}
__device__ __forceinline__ float row16_max(float x) {
    x = fmaxf(x, dppf<0xB1>(x));
    x = fmaxf(x, dppf<0x4E>(x));
    x = fmaxf(x, dppf<0x141>(x));
    x = fmaxf(x, dppf<0x140>(x));
    return x;
}

// ---------------- prep: Wfused = Wp2 @ Ww1, cfused = bp2 @ Ww1 + bw1 ----------------
__global__ void fuse_kernel(const float* __restrict__ Wp2, const float* __restrict__ Ww1,
                            const float* __restrict__ bp2, const float* __restrict__ bw1,
                            float* __restrict__ Wfused, float* __restrict__ cfused)
{
    const int o = blockIdx.x*256 + threadIdx.x;
    if (o < CC*GG) {
        const int i = o / GG, g = o % GG;
        float s = 0.f;
        for (int j = 0; j < CC; ++j) s += Wp2[i*CC + j] * Ww1[j*GG + g];
        Wfused[o] = s;
    }
    if (o < GG) {
        float s = bw1[o];
        for (int j = 0; j < CC; ++j) s += bp2[j] * Ww1[j*GG + o];
        cfused[o] = s;
    }
}

// ---------------- Kernel A: q/k/v projections via MFMA ----------------
__global__ __launch_bounds__(256) void qkv_mfma(
    const float* __restrict__ q, const float* __restrict__ kx, const float* __restrict__ v,
    const float* __restrict__ Wq, const float* __restrict__ bq, const float* __restrict__ gq, const float* __restrict__ betaq,
    const float* __restrict__ Wk, const float* __restrict__ bk, const float* __restrict__ gk, const float* __restrict__ betak,
    const float* __restrict__ Wv, const float* __restrict__ bv,
    const float* __restrict__ Ww1,
    float* __restrict__ valout, float* __restrict__ qw1out, float* __restrict__ kw1out)
{
    __shared__ ushort sWf[18*64*8];     // W B-frags bf16, 18 KB
    __shared__ float sbias[CC], sg[CC], sbeta[CC];
    __shared__ float sx[4][SS*CP];      // per-wave C/D->A transpose buffer

    const int p = blockIdx.y;
    const float* X; const float* W; const float* b;
    const float* g = nullptr; const float* beta = nullptr;
    if (p == 0)      { X = q;  W = Wq; b = bq; g = gq; beta = betaq; }
    else if (p == 1) { X = kx; W = Wk; b = bk; g = gk; beta = betak; }
    else             { X = v;  W = Wv; b = bv; }
    const bool has_ln = (p < 2);
    float* w1out = (p == 0) ? qw1out : kw1out;

    const int t = threadIdx.x;
    if (t < CC) {
        sbias[t] = b[t];
        if (has_ln) { sg[t] = g[t]; sbeta[t] = beta[t]; }
    }
    for (int idx = t; idx < 18*64; idx += 256) {
        const int ntkb = idx >> 6, ln = idx & 63;
        const int nt = ntkb / 3, kb = ntkb - nt*3;
        const int ccol  = nt*16 + (ln & 15);
        const int kbase = kb*32 + (ln >> 4)*8;
        ushort* dst = sWf + idx*8;
        #pragma unroll
        for (int j = 0; j < 8; ++j) dst[j] = (ushort)f2bf(W[(size_t)(kbase + j)*CC + ccol]);
    }

    const int lane = t & 63, w = t >> 6;
    const int c16 = lane & 15, quad = lane >> 4;

    bf16x8 Ww1f[3];
    if (has_ln) {
        #pragma unroll
        for (int kb = 0; kb < 3; ++kb)
            #pragma unroll
            for (int j = 0; j < 8; ++j)
                Ww1f[kb][j] = (c16 < GG) ? f2bf(Ww1[(size_t)(kb*32 + quad*8 + j)*GG + c16]) : (short)0;
    }

    __syncthreads();

    const f32x4 zero4 = {0.f, 0.f, 0.f, 0.f};
    float* sxw = sx[w];
    const int tile = blockIdx.x*4 + w;     // exactly 2500 tiles
    const int row0 = tile * 16;

    const float* xr = X + (size_t)(row0 + c16)*CC;
    bf16x8 Af[3];
    #pragma unroll
    for (int kb = 0; kb < 3; ++kb) {
        const float4 a0 = *(const float4*)(xr + kb*32 + quad*8);
        const float4 a1 = *(const float4*)(xr + kb*32 + quad*8 + 4);
        Af[kb][0] = f2bf(a0.x); Af[kb][1] = f2bf(a0.y);
        Af[kb][2] = f2bf(a0.z); Af[kb][3] = f2bf(a0.w);
        Af[kb][4] = f2bf(a1.x); Af[kb][5] = f2bf(a1.y);
        Af[kb][6] = f2bf(a1.z); Af[kb][7] = f2bf(a1.w);
    }

    f32x4 acc[6];
    #pragma unroll
    for (int nt = 0; nt < 6; ++nt) acc[nt] = zero4;
    #pragma unroll
    for (int kb = 0; kb < 3; ++kb)
        #pragma unroll
        for (int nt = 0; nt < 6; ++nt) {
            const bf16x8 bf = *(const bf16x8*)(sWf + ((nt*3 + kb)*64 + lane)*8);
            acc[nt] = __builtin_amdgcn_mfma_f32_16x16x32_bf16(Af[kb], bf, acc[nt], 0, 0, 0);
        }

    #pragma unroll
    for (int nt = 0; nt < 6; ++nt) {
        const float bb = sbias[nt*16 + c16];
        #pragma unroll
        for (int r = 0; r < 4; ++r) acc[nt][r] += bb;
    }

    if (has_ln) {
        #pragma unroll
        for (int r = 0; r < 4; ++r) {
            float sum = 0.f, sq = 0.f;
            #pragma unroll
            for (int nt = 0; nt < 6; ++nt) { float x = acc[nt][r]; sum += x; sq += x*x; }
            sum = row16_sum(sum); sq = row16_sum(sq);
            const float mu  = sum * (1.f/96.f);
            const float var = sq * (1.f/96.f) - mu*mu;
            const float rs  = rsqrtf(var + 1e-5f);
            #pragma unroll
            for (int nt = 0; nt < 6; ++nt) {
                const int c = nt*16 + c16;
                acc[nt][r] = fmaxf((acc[nt][r] - mu)*rs*sg[c] + sbeta[c], 0.f);
            }
        }
        // C/D -> per-wave LDS -> A-frags -> @Ww1
        #pragma unroll
        for (int nt = 0; nt < 6; ++nt)
            #pragma unroll
            for (int r = 0; r < 4; ++r)
                sxw[(quad*4 + r)*CP + nt*16 + c16] = acc[nt][r];

        bf16x8 aA[3];
        #pragma unroll
        for (int kb = 0; kb < 3; ++kb) {
            const float4 a0 = *(const float4*)(sxw + c16*CP + kb*32 + quad*8);
            const float4 a1 = *(const float4*)(sxw + c16*CP + kb*32 + quad*8 + 4);
            aA[kb][0] = f2bf(a0.x); aA[kb][1] = f2bf(a0.y);
            aA[kb][2] = f2bf(a0.z); aA[kb][3] = f2bf(a0.w);
            aA[kb][4] = f2bf(a1.x); aA[kb][5] = f2bf(a1.y);
            aA[kb][6] = f2bf(a1.z); aA[kb][7] = f2bf(a1.w);
        }
        f32x4 o = zero4;
        #pragma unroll
        for (int kb = 0; kb < 3; ++kb)
            o = __builtin_amdgcn_mfma_f32_16x16x32_bf16(aA[kb], Ww1f[kb], o, 0, 0, 0);
        if (c16 < GG) {
            #pragma unroll
            for (int r = 0; r < 4; ++r)
                w1out[(size_t)(row0 + quad*4 + r)*GG + c16] = o[r];
        }
    } else {
        #pragma unroll
        for (int r = 0; r < 4; ++r)
            #pragma unroll
            for (int nt = 0; nt < 6; ++nt)
                valout[(size_t)(row0 + quad*4 + r)*CC + nt*16 + c16] = acc[nt][r];
    }
}

// ---------------- Kernel B: grouped vector attention, one node per wave ----------------
// NOTE: no forced min-occupancy — R4 showed forcing 3 waves/EU at ~100 live regs
// spills to scratch (FETCH 1.35 GB). Pressure is reduced structurally instead:
// peb MFMAs deferred & consumed 2 nt-tiles at a time; Wfused frags in LDS.
__global__ __launch_bounds__(256) void attn2(
    const float* __restrict__ xyz, const int* __restrict__ refidx,
    const float* __restrict__ Wp1, const float* __restrict__ bp1,
    const float* __restrict__ gp,  const float* __restrict__ betap,
    const float* __restrict__ Wp2, const float* __restrict__ bp2,
    const float* __restrict__ gw,  const float* __restrict__ betaw,
    const float* __restrict__ Ww2, const float* __restrict__ bw2,
    const float* __restrict__ Wfused, const float* __restrict__ cfused,
    const float* __restrict__ valw, const float* __restrict__ kw1w, const float* __restrict__ qw1w,
    float* __restrict__ out)
{
    __shared__ float  sWp1[3*CC];
    __shared__ float  sbp1[CC], sgp[CC], sbetap[CC], sbp2[CC];
    __shared__ float  sWw2[GG*GG];
    __shared__ float  sgw[16], sbetaw[16], sbw2[16], scf[16];
    __shared__ ushort sWp2f[18*64*8];     // Wp2 B-frags bf16, 18 KB
    __shared__ ushort sWffl[3*64*8];      // Wfused B-frags bf16, 3 KB
    __shared__ float  ybv[4][SS*GG];
    __shared__ float  swv[4][SS*GG];
    __shared__ float  soutb[4][CC];

    const int t = threadIdx.x;
    for (int i = t; i < 3*CC; i += 256) sWp1[i] = Wp1[i];
    if (t < CC) { sbp1[t] = bp1[t]; sgp[t] = gp[t]; sbetap[t] = betap[t]; sbp2[t] = bp2[t]; }
    if (t < GG*GG) sWw2[t] = Ww2[t];
    if (t < 16) {
        sgw[t]    = (t < GG) ? gw[t]     : 0.f;
        sbetaw[t] = (t < GG) ? betaw[t]  : 0.f;
        sbw2[t]   = (t < GG) ? bw2[t]    : 0.f;
        scf[t]    = (t < GG) ? cfused[t] : 0.f;
    }
    for (int idx = t; idx < 18*64; idx += 256) {
        const int ntkb = idx >> 6, ln = idx & 63;
        const int nt = ntkb / 3, kb = ntkb - nt*3;
        const int ccol  = nt*16 + (ln & 15);
        const int kbase = kb*32 + (ln >> 4)*8;
        ushort* dst = sWp2f + idx*8;
        #pragma unroll
        for (int j = 0; j < 8; ++j) dst[j] = (ushort)f2bf(Wp2[(size_t)(kbase + j)*CC + ccol]);
    }
    if (t < 3*64) {   // Wfused frags (cols 12..15 zero)
        const int kb = t >> 6, ln = t & 63;
        const int col   = ln & 15;
        const int kbase = kb*32 + (ln >> 4)*8;
        ushort* dst = sWffl + t*8;
        #pragma unroll
        for (int j = 0; j < 8; ++j)
            dst[j] = (col < GG) ? (ushort)f2bf(Wfused[(size_t)(kbase + j)*GG + col]) : (ushort)0;
    }

    const int lane = t & 63, w = t >> 6;
    const int c16 = lane & 15, quad = lane >> 4;
    const int gcl = (c16 < GG) ? c16 : (GG-1);

    __syncthreads();   // staging done; below is wave-synchronous

    float* yb = ybv[w];
    float* sw = swv[w];
    float* so = soutb[w];
    const f32x4 zero4 = {0.f, 0.f, 0.f, 0.f};

    const int nbase = blockIdx.x*16 + w*4;

    for (int i = 0; i < 4; ++i) {
        const int n = nbase + i;

        // ---- per-lane neighbor (s = c16) ----
        const int   id   = refidx[(size_t)n*SS + c16];
        const float m    = (id >= 0) ? 1.f : 0.f;
        const int   safe = (id < 0) ? 0 : id;

        // ---- C/D-layout epilogue operands (s = quad*4+r) ----
        float kwv[4];
        #pragma unroll
        for (int r = 0; r < 4; ++r) {
            const int sid = refidx[(size_t)n*SS + quad*4 + r];
            const float mr = (sid >= 0) ? 1.f : 0.f;
            const int sf = (sid < 0) ? 0 : sid;
            kwv[r] = kw1w[(size_t)sf*GG + gcl] * mr;
        }
        const float qv = qw1w[(size_t)n*GG + gcl];

        // ---- val gather (A-layout: lane s=c16, cols kb*32+quad*8+..) ----
        const float* vr = valw + (size_t)safe*CC;
        float4 v0[3], v1[3];
        #pragma unroll
        for (int kb = 0; kb < 3; ++kb) {
            v0[kb] = *(const float4*)(vr + kb*32 + quad*8);
            v1[kb] = *(const float4*)(vr + kb*32 + quad*8 + 4);
        }

        const float px = (xyz[(size_t)safe*3 + 0] - xyz[(size_t)n*3 + 0]) * m;
        const float py = (xyz[(size_t)safe*3 + 1] - xyz[(size_t)n*3 + 1]) * m;
        const float pz = (xyz[(size_t)safe*3 + 2] - xyz[(size_t)n*3 + 2]) * m;

        // ---- t1 = relu(ln(pos @ Wp1 + bp1)) in A-frag layout ----
        float tv[3][8];
        float sum = 0.f, sq = 0.f;
        #pragma unroll
        for (int kb = 0; kb < 3; ++kb)
            #pragma unroll
            for (int j = 0; j < 8; ++j) {
                const int c = kb*32 + quad*8 + j;
                const float x = sbp1[c] + px*sWp1[c] + py*sWp1[CC + c] + pz*sWp1[2*CC + c];
                tv[kb][j] = x; sum += x; sq += x*x;
            }
        sum += __shfl_xor(sum, 16, 64); sq += __shfl_xor(sq, 16, 64);
        sum += __shfl_xor(sum, 32, 64); sq += __shfl_xor(sq, 32, 64);
        const float mu1  = sum * (1.f/96.f);
        const float var1 = sq * (1.f/96.f) - mu1*mu1;
        const float rs1  = rsqrtf(var1 + 1e-5f);
        bf16x8 t1A[3];
        #pragma unroll
        for (int kb = 0; kb < 3; ++kb)
            #pragma unroll
            for (int j = 0; j < 8; ++j) {
                const int c = kb*32 + quad*8 + j;
                t1A[kb][j] = f2bf(fmaxf((tv[kb][j] - mu1)*rs1*sgp[c] + sbetap[c], 0.f));
            }

        // ---- t2 = t1 @ Wfused (frags from LDS) ----
        f32x4 t2 = zero4;
        #pragma unroll
        for (int kb = 0; kb < 3; ++kb) {
            const bf16x8 wf = *(const bf16x8*)(sWffl + (kb*64 + lane)*8);
            t2 = __builtin_amdgcn_mfma_f32_16x16x32_bf16(t1A[kb], wf, t2, 0, 0, 0);
        }

        // ---- t2 epilogue: + m*kw1[safe[s]][g] - qw1[n][g] + cfused[g] ----
        #pragma unroll
        for (int r = 0; r < 4; ++r)
            t2[r] += kwv[r] - qv + scf[c16];

        // LN over G=12 (rows s=quad*4+r, lane col g=c16) via DPP
        #pragma unroll
        for (int r = 0; r < 4; ++r) {
            const float x = (c16 < GG) ? t2[r] : 0.f;
            const float s1 = row16_sum(x);
            const float s2 = row16_sum(x*x);
            const float mu  = s1 * (1.f/12.f);
            const float var = s2 * (1.f/12.f) - mu*mu;
            const float rs  = rsqrtf(var + 1e-5f);
            const float y   = fmaxf((t2[r] - mu)*rs*sgw[c16] + sbetaw[c16], 0.f);
            if (c16 < GG) yb[(quad*4 + r)*GG + c16] = y;
        }

        // w3 = y @ Ww2 + bw2 ; lane covers s=c16, g' in {quad, quad+4, quad+8}
        float w3[3];
        #pragma unroll
        for (int gi = 0; gi < 3; ++gi) {
            const int gpp = quad + gi*4;
            float a2 = sbw2[gpp];
            #pragma unroll
            for (int gg2 = 0; gg2 < GG; ++gg2)
                a2 += yb[c16*GG + gg2] * sWw2[gg2*GG + gpp];
            w3[gi] = a2;
        }

        // softmax over s (c16-lanes), then * mask — all DPP
        #pragma unroll
        for (int gi = 0; gi < 3; ++gi) {
            const float mx = row16_max(w3[gi]);
            const float e  = __expf(w3[gi] - mx);
            const float tot = row16_sum(e);
            w3[gi] = e / tot * m;
        }
        // broadcast w to LDS for the C/D-layout peb reduction
        #pragma unroll
        for (int gi = 0; gi < 3; ++gi)
            sw[c16*GG + quad + 4*gi] = w3[gi];

        // ---- valpart: sum_s val[s][col]*w[s][g(col)] via DPP allreduce ----
        #pragma unroll
        for (int kb = 0; kb < 3; ++kb) {
            const float pj[8] = {v0[kb].x, v0[kb].y, v0[kb].z, v0[kb].w,
                                 v1[kb].x, v1[kb].y, v1[kb].z, v1[kb].w};
            #pragma unroll
            for (int j = 0; j < 8; ++j) {
                const float pr = row16_sum(pj[j] * w3[kb]);
                if (c16 == 0) so[kb*32 + quad*8 + j] = pr;
            }
        }

        // ---- pebpart: deferred MFMAs, 2 nt-tiles at a time (8 acc VGPRs live) ----
        #pragma unroll
        for (int ntp = 0; ntp < 3; ++ntp) {
            const int nt0 = 2*ntp, nt1 = 2*ntp + 1;
            f32x4 pa = zero4, pb = zero4;
            #pragma unroll
            for (int kb = 0; kb < 3; ++kb) {
                const bf16x8 bfa = *(const bf16x8*)(sWp2f + ((nt0*3 + kb)*64 + lane)*8);
                const bf16x8 bfb = *(const bf16x8*)(sWp2f + ((nt1*3 + kb)*64 + lane)*8);
                pa = __builtin_amdgcn_mfma_f32_16x16x32_bf16(t1A[kb], bfa, pa, 0, 0, 0);
                pb = __builtin_amdgcn_mfma_f32_16x16x32_bf16(t1A[kb], bfb, pb, 0, 0, 0);
            }
            #pragma unroll
            for (int h = 0; h < 2; ++h) {
                const int nt = (h == 0) ? nt0 : nt1;
                const f32x4& pc = (h == 0) ? pa : pb;
                const float b2   = sbp2[nt*16 + c16];
                const int   gidx = 2*nt + (c16 >> 3);
                float a2 = 0.f;
                #pragma unroll
                for (int r = 0; r < 4; ++r)
                    a2 += (pc[r] + b2) * sw[(quad*4 + r)*GG + gidx];
                a2 += __shfl_xor(a2, 16, 64);
                a2 += __shfl_xor(a2, 32, 64);
                if (quad == 0) so[nt*16 + c16] += a2;
            }
        }

        if (lane < 24) {
            const float4 o4 = ((const float4*)so)[lane];
            ((float4*)(out + (size_t)n*CC))[lane] = o4;
        }
    }
}

extern "C" void kernel_launch(void* const* d_in, const int* in_sizes, int n_in,
                              void* d_out, int out_size, void* d_ws, size_t ws_size,
                              hipStream_t stream)
{
    const float* q     = (const float*)d_in[0];
    const float* k     = (const float*)d_in[1];
    const float* v     = (const float*)d_in[2];
    const float* xyz   = (const float*)d_in[3];
    const int*   ridx  = (const int*)d_in[4];
    const float* Wq    = (const float*)d_in[5];
    const float* bq    = (const float*)d_in[6];
    const float* gq    = (const float*)d_in[7];
    const float* betaq = (const float*)d_in[8];
    const float* Wk    = (const float*)d_in[9];
    const float* bk    = (const float*)d_in[10];
    const float* gk    = (const float*)d_in[11];
    const float* betak = (const float*)d_in[12];
    const float* Wv    = (const float*)d_in[13];
    const float* bv    = (const float*)d_in[14];
    const float* Wp1   = (const float*)d_in[15];
    const float* bp1   = (const float*)d_in[16];
    const float* gp    = (const float*)d_in[17];
    const float* betap = (const float*)d_in[18];
    const float* Wp2   = (const float*)d_in[19];
    const float* bp2   = (const float*)d_in[20];
    const float* Ww1   = (const float*)d_in[21];
    const float* bw1   = (const float*)d_in[22];
    const float* gw    = (const float*)d_in[23];
    const float* betaw = (const float*)d_in[24];
    const float* Ww2   = (const float*)d_in[25];
    const float* bw2   = (const float*)d_in[26];
    float* out = (float*)d_out;

    float* ws = (float*)d_ws;
    float* valw   = ws;                                    // [N, 96]
    float* kw1w   = ws + (size_t)NN*CC;                    // [N, 12]
    float* qw1w   = ws + (size_t)NN*CC + (size_t)NN*GG;    // [N, 12]
    float* Wfused = ws + (size_t)NN*CC + 2*(size_t)NN*GG;  // [96, 12]
    float* cfused = Wfused + CC*GG;                        // [12]

    fuse_kernel<<<dim3(5, 1, 1), 256, 0, stream>>>(Wp2, Ww1, bp2, bw1, Wfused, cfused);

    qkv_mfma<<<dim3(625, 3, 1), 256, 0, stream>>>(
        q, k, v, Wq, bq, gq, betaq, Wk, bk, gk, betak, Wv, bv, Ww1,
        valw, qw1w, kw1w);

    attn2<<<dim3(2500, 1, 1), 256, 0, stream>>>(
        xyz, ridx, Wp1, bp1, gp, betap, Wp2, bp2,
        gw, betaw, Ww2, bw2, Wfused, cfused,
        valw, kw1w, qw1w, out);
}